// Round 8
// baseline (107.580 us; speedup 1.0000x reference)
//
#include <hip/hip_runtime.h>
#include <math.h>

// NLM denoise: x [2,3,512,512] f32, SWS=11 (121 shifts), TWS=5, circular wrap.
// d2 = ||Pc||^2 + ||Ps||^2 - 2<Pc,Ps>; cross-terms via v_dot2_f32_f16 on f16
// pair table; norms via precomputed vertical 5-sum table V (K^2-prescaled).
// w = exp2(-sqrt(K2*d2)); out = clip(sum w*x / sum w, 0, 1)
// mc=4, 256-thr blocks (2 waves/SIMD, thread-capped). xs processed in PAIRS
// (NU=2 template) -> two independent dot2/LDS streams interleaved for ILP;
// VGPR headroom to 256 at 2 waves/SIMD makes this free occupancy-wise.

#define H_IMG 512
#define W_IMG 512
#define MASK  511
#define HWSZ  (H_IMG * W_IMG)
#define TILE  32
#define HALO  7
#define XD    46          // TILE + 2*HALO
#define YSTR  48          // padded col-stride for yf / ldsY2
#define HSTR  44          // col-stride for ldsH (42 cols used)
#define VSTR  44          // col-stride for ldsV (42 cols used)

typedef _Float16 h2 __attribute__((ext_vector_type(2)));

__device__ __forceinline__ float fdot2(h2 a, h2 b, float c) {
#if __has_builtin(__builtin_amdgcn_fdot2)
    return __builtin_amdgcn_fdot2(a, b, c, false);
#else
    return c + (float)a.x * (float)b.x + (float)a.y * (float)b.y;
#endif
}

__device__ __forceinline__ float fast_exp2(float x) {
#if __has_builtin(__builtin_amdgcn_exp2f)
    return __builtin_amdgcn_exp2f(x);
#else
    return __expf(x * 0.6931471805599453f);
#endif
}

#define K2C   0.23126321070979063f    // (log2(e)/3)^2
#define N2K2 -0.46252642141958126f    // -2*K2C

template <int NU>
__device__ __forceinline__ void nlm_xs_group(
    int xs0, int jl, int il,
    const unsigned* __restrict__ ldsY2,
    const float*    __restrict__ ldsV,
    const float4*   __restrict__ ldsX,
    const h2 (&cyP)[8][3], const float (&Vc)[4],
    float (&num0)[4], float (&num1)[4], float (&num2)[4], float (&den)[4])
{
    h2     swP[NU][8][3];          // shifted-y f16-pair rings
    float  Wr[NU][4];              // V-table rings
    float4 xw[NU][4];              // x-neighbor rings
    int    jc[NU], xjc[NU];

    #pragma unroll
    for (int u = 0; u < NU; ++u) {
        const int xs = xs0 + u;
        jc[u]  = jl - xs - 2;
        xjc[u] = jl - xs;
        #pragma unroll
        for (int t = 0; t < 8; ++t) {
            int base = (il - 7 + t) * YSTR + jc[u];
            swP[u][t][0] = __builtin_bit_cast(h2, ldsY2[base]);
            swP[u][t][1] = __builtin_bit_cast(h2, ldsY2[base + 2]);
            swP[u][t][2] = __builtin_bit_cast(h2, ldsY2[base + 4]);
        }
        #pragma unroll
        for (int t = 0; t < 4; ++t) {
            Wr[u][t] = ldsV[(il - 7 + t) * VSTR + jc[u]];
            xw[u][t] = ldsX[(il - 5 + t) * XD + xjc[u]];
        }
    }

    #pragma unroll
    for (int k = 0; k <= 10; ++k) {     // ys = 5 - k
        // prefetch next step's ring entries (both streams)
        h2 nsw[NU][3]; float nWv[NU]; float4 nxw[NU];
        if (k < 10) {
            #pragma unroll
            for (int u = 0; u < NU; ++u) {
                int base = (il + k + 1) * YSTR + jc[u];
                nsw[u][0] = __builtin_bit_cast(h2, ldsY2[base]);
                nsw[u][1] = __builtin_bit_cast(h2, ldsY2[base + 2]);
                nsw[u][2] = __builtin_bit_cast(h2, ldsY2[base + 4]);
                nWv[u] = ldsV[(il + k - 3) * VSTR + jc[u]];
                nxw[u] = ldsX[(il + k - 1) * XD + xjc[u]];
            }
        }

        // row-dot cross terms, two independent chains interleaved
        float s[NU][8];
        #pragma unroll
        for (int t = 0; t < 8; ++t) {
            const int m = (t + k) & 7;
            #pragma unroll
            for (int u = 0; u < NU; ++u)
                s[u][t] = fdot2(cyP[t][0], swP[u][m][0],
                          fdot2(cyP[t][1], swP[u][m][1],
                          fdot2(cyP[t][2], swP[u][m][2], 0.f)));
        }

        #pragma unroll
        for (int u = 0; u < NU; ++u) {
            float S0 = ((s[u][0] + s[u][1]) + (s[u][2] + s[u][3])) + s[u][4];
            float S1 = S0 - s[u][0] + s[u][5];
            float S2 = S1 - s[u][1] + s[u][6];
            float S3 = S2 - s[u][2] + s[u][7];

            float d2a[4];
            d2a[0] = fmaf(N2K2, S0, Vc[0] + Wr[u][k & 3]);
            d2a[1] = fmaf(N2K2, S1, Vc[1] + Wr[u][(k + 1) & 3]);
            d2a[2] = fmaf(N2K2, S2, Vc[2] + Wr[u][(k + 2) & 3]);
            d2a[3] = fmaf(N2K2, S3, Vc[3] + Wr[u][(k + 3) & 3]);

            #pragma unroll
            for (int o = 0; o < 4; ++o) {
                float sd = __builtin_amdgcn_sqrtf(__builtin_fabsf(d2a[o]));
                float w  = fast_exp2(-sd);
                float4 xv = xw[u][(k + o) & 3];
                num0[o] = fmaf(w, xv.x, num0[o]);
                num1[o] = fmaf(w, xv.y, num1[o]);
                num2[o] = fmaf(w, xv.z, num2[o]);
                den[o] += w;
            }
        }

        // commit prefetched ring entries
        if (k < 10) {
            #pragma unroll
            for (int u = 0; u < NU; ++u) {
                swP[u][k & 7][0] = nsw[u][0];
                swP[u][k & 7][1] = nsw[u][1];
                swP[u][k & 7][2] = nsw[u][2];
                Wr[u][k & 3] = nWv[u];
                xw[u][k & 3] = nxw[u];
            }
        }
    }
}

__global__ __launch_bounds__(256, 2)
void nlm_kernel(const float* __restrict__ x, float* __restrict__ out) {
    __shared__ float4   ldsX[XD * XD];        // 33856 B
    __shared__ float    ldsYf[XD * YSTR];     //  8832 B (f32 y, 47 cols used)
    __shared__ unsigned ldsY2[XD * YSTR];     //  8832 B (f16 pair (y_c,y_{c+1}))
    __shared__ float    ldsH[XD * HSTR];      //  8096 B (row 5-norms)
    __shared__ float    ldsV[42 * VSTR];      //  7392 B (K2 * vertical 5-sum of H)
                                              //  total 67008 B -> 2 blocks/CU

    const int n  = blockIdx.z;
    const int ti = blockIdx.y * TILE;
    const int tj = blockIdx.x * TILE;
    const int tx = threadIdx.x;            // 0..31
    const int ty = threadIdx.y;            // 0..7
    const int tid = ty * 32 + tx;

    const float* xb = x + (size_t)n * 3 * HWSZ;

    // ---- A: stage x (tile + halo 7), packed float4 ----
    for (int e = tid; e < XD * XD; e += 256) {
        int r = e / XD, c = e - r * XD;
        int gi = (ti + r - HALO) & MASK;
        int gj = (tj + c - HALO) & MASK;
        size_t o = (size_t)gi * W_IMG + gj;
        ldsX[e] = make_float4(xb[o], xb[o + HWSZ], xb[o + 2 * HWSZ], 0.f);
    }
    __syncthreads();

    // ---- B: luminance (f32), 46 rows x 47 cols (col 46 dup, masked later) ----
    for (int e = tid; e < XD * 47; e += 256) {
        int r = e / 47, c = e - r * 47;
        int cs = (c == 46) ? 45 : c;
        float4 v = ldsX[r * XD + cs];
        float rr = fminf(fmaxf(v.x, 0.f), 1.f);
        float gg = fminf(fmaxf(v.y, 0.f), 1.f);
        float bb = fminf(fmaxf(v.z, 0.f), 1.f);
        ldsYf[r * YSTR + c] = 0.299f * rr + 0.587f * gg + 0.114f * bb;
    }
    __syncthreads();

    // ---- C: f16 pair table: entry[r][c] = (y(c), y(c+1)) ----
    for (int e = tid; e < XD * XD; e += 256) {   // 46x46 entries
        int r = e / XD, c = e - r * XD;
        h2 p;
        p.x = (_Float16)ldsYf[r * YSTR + c];
        p.y = (_Float16)ldsYf[r * YSTR + c + 1];
        ldsY2[r * YSTR + c] = __builtin_bit_cast(unsigned, p);
    }
    __syncthreads();

    // ---- D: row-norm H(r,c) = sum_{d=0..4} yh(r,c+d)^2 ----
    for (int e = tid; e < XD * 42; e += 256) {
        int r = e / 42, c = e - r * 42;
        h2 a  = __builtin_bit_cast(h2, ldsY2[r * YSTR + c]);
        h2 b  = __builtin_bit_cast(h2, ldsY2[r * YSTR + c + 2]);
        h2 cc = __builtin_bit_cast(h2, ldsY2[r * YSTR + c + 4]);
        float x0 = (float)a.x, x1 = (float)a.y;
        float x2 = (float)b.x, x3 = (float)b.y;
        float x4 = (float)cc.x;
        ldsH[r * HSTR + c] = x0*x0 + x1*x1 + x2*x2 + x3*x3 + x4*x4;
    }
    __syncthreads();

    // ---- E: V(r,c) = K2 * sum_{t=0..4} H(r+t,c) ----
    for (int e = tid; e < 42 * 42; e += 256) {
        int r = e / 42, c = e - r * 42;
        const float* hp = &ldsH[r * HSTR + c];
        float s = ((hp[0] + hp[HSTR]) + (hp[2*HSTR] + hp[3*HSTR])) + hp[4*HSTR];
        ldsV[r * VSTR + c] = K2C * s;
    }
    __syncthreads();

    const int jl = tx + HALO;          // LDS col of this thread's column
    const int il = ty * 4 + HALO;      // LDS row of first of 4 outputs

    // center patch as f16 pairs + K2-prescaled center norms (from V table)
    h2 cyP[8][3];
    float Vc[4];
    #pragma unroll
    for (int t = 0; t < 8; ++t) {
        int base = (il - 2 + t) * YSTR + (jl - 2);
        cyP[t][0] = __builtin_bit_cast(h2, ldsY2[base]);
        cyP[t][1] = __builtin_bit_cast(h2, ldsY2[base + 2]);
        h2 z = __builtin_bit_cast(h2, ldsY2[base + 4]);
        z.y = (_Float16)0.f;
        cyP[t][2] = z;
    }
    #pragma unroll
    for (int o = 0; o < 4; ++o)
        Vc[o] = ldsV[(il - 2 + o) * VSTR + (jl - 2)];

    float num0[4] = {0.f, 0.f, 0.f, 0.f};
    float num1[4] = {0.f, 0.f, 0.f, 0.f};
    float num2[4] = {0.f, 0.f, 0.f, 0.f};
    float den[4]  = {0.f, 0.f, 0.f, 0.f};

    // xs = -5 alone, then pairs (-4,-3),(-2,-1),(0,1),(2,3),(4,5)
    nlm_xs_group<1>(-5, jl, il, ldsY2, ldsV, ldsX, cyP, Vc,
                    num0, num1, num2, den);
    #pragma unroll 1
    for (int xp = -4; xp <= 4; xp += 2)
        nlm_xs_group<2>(xp, jl, il, ldsY2, ldsV, ldsX, cyP, Vc,
                        num0, num1, num2, den);

    // ---- epilogue ----
    float* ob = out + (size_t)n * 3 * HWSZ;
    #pragma unroll
    for (int o = 0; o < 4; ++o) {
        int gi = ti + ty * 4 + o;
        int gj = tj + tx;
        size_t off = (size_t)gi * W_IMG + gj;
        float inv = __builtin_amdgcn_rcpf(den[o]);
        float v0 = fminf(fmaxf(num0[o] * inv, 0.f), 1.f);
        float v1 = fminf(fmaxf(num1[o] * inv, 0.f), 1.f);
        float v2 = fminf(fmaxf(num2[o] * inv, 0.f), 1.f);
        ob[off]            = v0;
        ob[off + HWSZ]     = v1;
        ob[off + 2 * HWSZ] = v2;
    }
}

extern "C" void kernel_launch(void* const* d_in, const int* in_sizes, int n_in,
                              void* d_out, int out_size, void* d_ws, size_t ws_size,
                              hipStream_t stream) {
    const float* x = (const float*)d_in[0];
    float* out = (float*)d_out;
    dim3 grid(W_IMG / TILE, H_IMG / TILE, 2);   // (16,16,2) = 512 blocks
    dim3 block(32, 8);                          // 256 threads, mc=4
    nlm_kernel<<<grid, block, 0, stream>>>(x, out);
}